// Round 4
// baseline (29.089 us; speedup 1.0000x reference)
//
#include <hip/hip_runtime.h>
#include <math.h>

#define NGRID 100

// One block per batch image. The full 100x100 fp32 image lives in LDS
// (40 KB of the 160 KB/CU). Each of the 1024 threads handles ~8 points:
// computes the fp64 kinematics ONCE per point (the round-3 gather kernel
// recomputed it 100x per point), early-outs on the doppler window test
// (~98% of points), and scatters survivors' ~16-bin range window into the
// LDS image via LDS atomics (a handful of active points per block -> no
// contention). The block then writes its whole image unconditionally, so no
// pre-zeroing memset dispatch and no global atomics: ONE dispatch total.
//
// Numerics: per-contribution fp64 chain identical to the round-2 kernel
// that passed at absmax 1.37e-2 (threshold 1.80e-2; the residual is the
// np float64 reference vs the bf16-floored threshold, i.e. reference-side
// fp32 noise, not ours). Only atomic summation order changes (~1e-7).
__global__ __launch_bounds__(1024) void isar_image(
        const float* __restrict__ pts,
        const float* __restrict__ nrm,
        const float* __restrict__ los,
        const float* __restrict__ spin,
        const float* __restrict__ omega,
        float* __restrict__ out,
        int N) {
    const int b = blockIdx.x;

    __shared__ float img[NGRID * NGRID];
    for (int t = threadIdx.x; t < NGRID * NGRID; t += blockDim.x) img[t] = 0.0f;
    __syncthreads();

    const double L0 = (double)los[0], L1 = (double)los[1], L2 = (double)los[2];
    const double S0 = (double)spin[0], S1 = (double)spin[1], S2 = (double)spin[2];
    const double Om = (double)omega[0];

    const double LAM  = 299792458.0 / 9.7e9;               // LAMBDA1
    const double dsig = LAM / 2.0 / Om / 160.0;            // doppler_res
    const double rsig = 299792458.0 / 4.8e9 / 2.0 * 5.0;   // RANGE_RES
    const double CUT  = 10.0;

    const float* ppb = pts + (size_t)b * N * 3;
    const float* nnb = nrm + (size_t)b * N * 3;

    for (int n = threadIdx.x; n < N; n += blockDim.x) {
        const float* pp = ppb + (size_t)n * 3;
        const double p0 = (double)pp[0], p1 = (double)pp[1], p2 = (double)pp[2];

        // v = cross(S, p); dop = -2 * Om * dot(L, v) / LAM
        const double v0 = S1 * p2 - S2 * p1;
        const double v1 = S2 * p0 - S0 * p2;
        const double v2 = S0 * p1 - S1 * p0;
        const double vrad = Om * (L0 * v0 + L1 * v1 + L2 * v2);
        const double dop = -2.0 * vrad / LAM;

        // doppler bin window: bins at -3 + i*(6/99); ~98% of points exit here
        const double ddlo = (dop - CUT * dsig + 3.0) * (99.0 / 6.0);
        const double ddhi = (dop + CUT * dsig + 3.0) * (99.0 / 6.0);
        if (ddhi < -1.0 || ddlo > (double)(NGRID + 1)) continue;
        const int i0 = max(0, (int)floor(ddlo) - 1);
        const int i1 = min(NGRID - 1, (int)ceil(ddhi) + 1);
        if (i0 > i1) continue;

        const double rng = L0 * p0 + L1 * p1 + L2 * p2;

        // range bin window: bins at -10 + j*(20/99)
        const double rrlo = (rng - CUT * rsig + 10.0) * (99.0 / 20.0);
        const double rrhi = (rng + CUT * rsig + 10.0) * (99.0 / 20.0);
        if (rrhi < -1.0 || rrlo > (double)(NGRID + 1)) continue;
        const int j0 = max(0, (int)floor(rrlo) - 1);
        const int j1 = min(NGRID - 1, (int)ceil(rrhi) + 1);
        if (j0 > j1) continue;

        const float* nn = nnb + (size_t)n * 3;
        double amp = -4.0 * (L0 * (double)nn[0] + L1 * (double)nn[1] +
                             L2 * (double)nn[2]);
        if (!(amp > 0.0)) continue;
        amp = fmin(amp, 1.0);

        for (int i = i0; i <= i1; ++i) {
            const double dbin = -3.0 + (double)i * (6.0 / 99.0);
            const double qd = (dop - dbin) / dsig;
            const double gd = exp(-0.5 * qd * qd);
            if (gd == 0.0) continue;
            for (int j = j0; j <= j1; ++j) {
                const double rbin = -10.0 + (double)j * (20.0 / 99.0);
                const double qr = (rng - rbin) / rsig;
                const double gr = exp(-0.5 * qr * qr);
                const float cf = (float)(amp * gr * gd);
                if (cf != 0.0f) atomicAdd(&img[i * NGRID + j], cf);
            }
        }
    }

    __syncthreads();
    float* outb = out + (size_t)b * NGRID * NGRID;
    for (int t = threadIdx.x; t < NGRID * NGRID; t += blockDim.x)
        outb[t] = img[t];
}

extern "C" void kernel_launch(void* const* d_in, const int* in_sizes, int n_in,
                              void* d_out, int out_size, void* d_ws, size_t ws_size,
                              hipStream_t stream) {
    const float* pts  = (const float*)d_in[0];   // [B,N,3]
    const float* nrm  = (const float*)d_in[1];   // [B,N,3]
    const float* los  = (const float*)d_in[2];   // [1,3]
    const float* spin = (const float*)d_in[3];   // [1,3]
    const float* om   = (const float*)d_in[4];   // [1,1]
    float* out = (float*)d_out;                  // [B,100,100]

    int BN = in_sizes[0] / 3;
    int B  = out_size / (NGRID * NGRID);
    if (B < 1) B = 1;
    int N  = BN / B;

    isar_image<<<B, 1024, 0, stream>>>(pts, nrm, los, spin, om, out, N);
}

// Round 5
// 16.344 us; speedup vs baseline: 1.7798x; 1.7798x over previous
//
#include <hip/hip_runtime.h>
#include <math.h>

#define NGRID 100

// Round-2 structure restored (best measured: 15.95 us vs 17.0 one-dispatch
// gather and 29.1 one-block-per-batch). Cross-round evidence: the harness
// graph-replay floor is ~14-15 us; in-graph dispatch count is worth <=1 us;
// kernel execution time is what differentiates. So: maximize TLP (1 thread
// per point, 125 blocks), compute kinematics exactly once per point, and
// keep the tiny memset for zeroing (its dispatch is nearly free).
//
// Micro-fix vs round 2: the doppler-window test (which needs only `pts`)
// runs BEFORE the normals load -> ~98% of points exit without touching
// `nrm`, halving gather traffic on the common path.
//
// Numerics: identical fp64 per-contribution chain as the round-2/3/4
// kernels (all passed at absmax 1.37e-2 vs threshold 1.80e-2; the residual
// is the fp64 np reference vs fp32-arithmetic noise on the reference side).
__global__ __launch_bounds__(256) void isar_splat(
        const float* __restrict__ pts,
        const float* __restrict__ nrm,
        const float* __restrict__ los,
        const float* __restrict__ spin,
        const float* __restrict__ omega,
        float* __restrict__ out,
        int BN, int N) {
    int idx = blockIdx.x * blockDim.x + threadIdx.x;
    if (idx >= BN) return;

    const double L0 = (double)los[0], L1 = (double)los[1], L2 = (double)los[2];
    const double S0 = (double)spin[0], S1 = (double)spin[1], S2 = (double)spin[2];
    const double Om = (double)omega[0];

    const float* pp = pts + (size_t)idx * 3;
    const double p0 = (double)pp[0], p1 = (double)pp[1], p2 = (double)pp[2];

    // v = cross(S, p); dop = -2 * Om * dot(L, v) / LAM
    const double v0 = S1 * p2 - S2 * p1;
    const double v1 = S2 * p0 - S0 * p2;
    const double v2 = S0 * p1 - S1 * p0;
    const double vrad = Om * (L0 * v0 + L1 * v1 + L2 * v2);

    const double LAM  = 299792458.0 / 9.7e9;               // LAMBDA1
    const double dop  = -2.0 * vrad / LAM;
    const double dsig = LAM / 2.0 / Om / 160.0;            // doppler_res
    const double rsig = 299792458.0 / 4.8e9 / 2.0 * 5.0;   // RANGE_RES
    const double CUT  = 10.0;

    // doppler bin window: bins at -3 + i*(6/99). ~98% of points exit here,
    // before the normals are ever loaded.
    const double ddlo = (dop - CUT * dsig + 3.0) * (99.0 / 6.0);
    const double ddhi = (dop + CUT * dsig + 3.0) * (99.0 / 6.0);
    if (ddhi < -1.0 || ddlo > (double)(NGRID + 1)) return;
    const int i0 = max(0, (int)floor(ddlo) - 1);
    const int i1 = min(NGRID - 1, (int)ceil(ddhi) + 1);
    if (i0 > i1) return;

    const double rng = L0 * p0 + L1 * p1 + L2 * p2;

    // range bin window: bins at -10 + j*(20/99)
    const double rrlo = (rng - CUT * rsig + 10.0) * (99.0 / 20.0);
    const double rrhi = (rng + CUT * rsig + 10.0) * (99.0 / 20.0);
    if (rrhi < -1.0 || rrlo > (double)(NGRID + 1)) return;
    const int j0 = max(0, (int)floor(rrlo) - 1);
    const int j1 = min(NGRID - 1, (int)ceil(rrhi) + 1);
    if (j0 > j1) return;

    const float* nn = nrm + (size_t)idx * 3;
    double amp = -4.0 * (L0 * (double)nn[0] + L1 * (double)nn[1] +
                         L2 * (double)nn[2]);
    if (!(amp > 0.0)) return;
    amp = fmin(amp, 1.0);

    const int b = idx / N;
    float* outb = out + (size_t)b * NGRID * NGRID;

    for (int i = i0; i <= i1; ++i) {
        const double dbin = -3.0 + (double)i * (6.0 / 99.0);
        const double qd = (dop - dbin) / dsig;
        const double gd = exp(-0.5 * qd * qd);
        if (gd == 0.0) continue;
        for (int j = j0; j <= j1; ++j) {
            const double rbin = -10.0 + (double)j * (20.0 / 99.0);
            const double qr = (rng - rbin) / rsig;
            const double gr = exp(-0.5 * qr * qr);
            const float cf = (float)(amp * gr * gd);
            if (cf != 0.0f) atomicAdd(&outb[i * NGRID + j], cf);
        }
    }
}

extern "C" void kernel_launch(void* const* d_in, const int* in_sizes, int n_in,
                              void* d_out, int out_size, void* d_ws, size_t ws_size,
                              hipStream_t stream) {
    const float* pts  = (const float*)d_in[0];   // [B,N,3]
    const float* nrm  = (const float*)d_in[1];   // [B,N,3]
    const float* los  = (const float*)d_in[2];   // [1,3]
    const float* spin = (const float*)d_in[3];   // [1,3]
    const float* om   = (const float*)d_in[4];   // [1,1]
    float* out = (float*)d_out;                  // [B,100,100]

    int BN = in_sizes[0] / 3;
    int B  = out_size / (NGRID * NGRID);
    if (B < 1) B = 1;
    int N  = BN / B;

    hipMemsetAsync(d_out, 0, (size_t)out_size * sizeof(float), stream);

    int threads = 256;
    int blocks = (BN + threads - 1) / threads;
    isar_splat<<<blocks, threads, 0, stream>>>(pts, nrm, los, spin, om, out, BN, N);
}